// Round 1
// baseline (1412.441 us; speedup 1.0000x reference)
//
#include <hip/hip_runtime.h>

// ---------------------------------------------------------------------------
// LightGCN-style propagation:
//   i_emb = item_w + content @ W^T + b ; x0 = [user_w ; i_emb]
//   x_{l+1} = A x_l (COO segment-sum) ; out = (x0+x1+x2+x3)/4
// Strategy: build CSR on-device once per launch (histogram + scan + scatter),
// then 3 gather-SpMM passes (wave-per-row, lane=dim, no float atomics).
// ---------------------------------------------------------------------------

__global__ void hist_kernel(const int* __restrict__ rows, int* __restrict__ counts, int E) {
    int stride = gridDim.x * blockDim.x;
    for (int e = blockIdx.x * blockDim.x + threadIdx.x; e < E; e += stride)
        atomicAdd(&counts[rows[e]], 1);
}

// Phase 1: per-block (1024-element chunk) sums
__global__ __launch_bounds__(256) void scan1_kernel(const int* __restrict__ counts,
                                                    int* __restrict__ bsum, int n) {
    __shared__ int sdata[256];
    int t = threadIdx.x;
    int i = blockIdx.x * 1024 + t * 4;
    int s = 0;
#pragma unroll
    for (int j = 0; j < 4; ++j) {
        int idx = i + j;
        if (idx < n) s += counts[idx];
    }
    sdata[t] = s;
    __syncthreads();
    for (int off = 128; off > 0; off >>= 1) {
        if (t < off) sdata[t] += sdata[t + off];
        __syncthreads();
    }
    if (t == 0) bsum[blockIdx.x] = sdata[0];
}

// Phase 2: exclusive scan of block sums (nb <= 1024), also writes row_ptr[n]=total
__global__ __launch_bounds__(1024) void scan2_kernel(int* __restrict__ bsum, int nb,
                                                     int* __restrict__ row_ptr, int nrows,
                                                     int total) {
    __shared__ int s[1024];
    int t = threadIdx.x;
    int v = (t < nb) ? bsum[t] : 0;
    s[t] = v;
    __syncthreads();
    for (int off = 1; off < 1024; off <<= 1) {
        int add = (t >= off) ? s[t - off] : 0;
        __syncthreads();
        s[t] += add;
        __syncthreads();
    }
    if (t < nb) bsum[t] = s[t] - v;  // exclusive
    if (t == 0) row_ptr[nrows] = total;
}

// Phase 3: full exclusive scan -> row_ptr[0..n-1]
__global__ __launch_bounds__(256) void scan3_kernel(const int* __restrict__ counts,
                                                    const int* __restrict__ bsum,
                                                    int* __restrict__ row_ptr, int n) {
    __shared__ int sdata[256];
    int t = threadIdx.x;
    int i = blockIdx.x * 1024 + t * 4;
    int v[4];
#pragma unroll
    for (int j = 0; j < 4; ++j) v[j] = (i + j < n) ? counts[i + j] : 0;
    int p0 = 0, p1 = v[0], p2 = v[0] + v[1], p3 = v[0] + v[1] + v[2];
    int s = p3 + v[3];
    sdata[t] = s;
    __syncthreads();
    for (int off = 1; off < 256; off <<= 1) {
        int add = (t >= off) ? sdata[t - off] : 0;
        __syncthreads();
        sdata[t] += add;
        __syncthreads();
    }
    int texcl = sdata[t] - s;  // exclusive among threads
    int base = bsum[blockIdx.x] + texcl;
    int p[4] = {p0, p1, p2, p3};
#pragma unroll
    for (int j = 0; j < 4; ++j)
        if (i + j < n) row_ptr[i + j] = base + p[j];
}

__global__ void scatter_kernel(const int* __restrict__ rows, const int* __restrict__ cols,
                               const float* __restrict__ vals, int* __restrict__ cursor,
                               int2* __restrict__ ecv, int E) {
    int stride = gridDim.x * blockDim.x;
    for (int e = blockIdx.x * blockDim.x + threadIdx.x; e < E; e += stride) {
        int r = rows[e];
        int p = atomicAdd(&cursor[r], 1);
        ecv[p] = make_int2(cols[e], __float_as_int(vals[e]));
    }
}

// Users: x0 = user_w ; out = 0.25*x0  (vectorized float4)
__global__ void init_users_kernel(const float4* __restrict__ uw, float4* __restrict__ x0,
                                  float4* __restrict__ out, int n4) {
    int stride = gridDim.x * blockDim.x;
    for (int i = blockIdx.x * blockDim.x + threadIdx.x; i < n4; i += stride) {
        float4 v = uw[i];
        x0[i] = v;
        float4 o;
        o.x = 0.25f * v.x; o.y = 0.25f * v.y; o.z = 0.25f * v.z; o.w = 0.25f * v.w;
        out[i] = o;
    }
}

// Items: x0 = item_w + content @ W^T + b ; out = 0.25*x0
// One wave per item (lane = output dim d); W staged in LDS with +1 pad.
__global__ __launch_bounds__(256) void init_items_kernel(
    const float* __restrict__ item_w, const float* __restrict__ content,
    const float* __restrict__ W, const float* __restrict__ bias, float* __restrict__ x0,
    float* __restrict__ out, int n_items, int base_row) {
    __shared__ float Ws[64 * 65];
    int t = threadIdx.x;
    for (int i = t; i < 4096; i += 256) {
        int r = i >> 6, c = i & 63;
        Ws[r * 65 + c] = W[i];  // W[d][k] at Ws[d*65+k]; bank=(d+k)%32 -> 2-way, free
    }
    __syncthreads();
    int lane = t & 63;
    int wid = t >> 6;
    float bl = bias[lane];
    int item0 = blockIdx.x * 64;
    for (int it = wid; it < 64; it += 4) {
        int item = item0 + it;
        if (item >= n_items) break;
        float c = content[item * 64 + lane];
        float acc = item_w[item * 64 + lane] + bl;
#pragma unroll
        for (int k = 0; k < 64; ++k) {
            float bc = __shfl(c, k, 64);
            acc = fmaf(bc, Ws[lane * 65 + k], acc);
        }
        int o = (base_row + item) * 64 + lane;
        x0[o] = acc;
        out[o] = 0.25f * acc;
    }
}

// Gather-SpMM: wave per row, lane = dim. y[row] = sum val*x[col]; out += 0.25*y.
__global__ __launch_bounds__(256) void spmm_kernel(const int* __restrict__ row_ptr,
                                                   const int2* __restrict__ ecv,
                                                   const float* __restrict__ x,
                                                   float* __restrict__ xn,
                                                   float* __restrict__ out, int nrows,
                                                   int write_next) {
    int row = blockIdx.x * 4 + (threadIdx.x >> 6);
    if (row >= nrows) return;
    int lane = threadIdx.x & 63;
    int s = row_ptr[row], e_end = row_ptr[row + 1];
    float a0 = 0.f, a1 = 0.f, a2 = 0.f, a3 = 0.f;
    int e = s;
    for (; e + 4 <= e_end; e += 4) {
        int2 p0 = ecv[e], p1 = ecv[e + 1], p2 = ecv[e + 2], p3 = ecv[e + 3];
        float x0v = x[p0.x * 64 + lane];
        float x1v = x[p1.x * 64 + lane];
        float x2v = x[p2.x * 64 + lane];
        float x3v = x[p3.x * 64 + lane];
        a0 = fmaf(__int_as_float(p0.y), x0v, a0);
        a1 = fmaf(__int_as_float(p1.y), x1v, a1);
        a2 = fmaf(__int_as_float(p2.y), x2v, a2);
        a3 = fmaf(__int_as_float(p3.y), x3v, a3);
    }
    for (; e < e_end; ++e) {
        int2 p = ecv[e];
        a0 = fmaf(__int_as_float(p.y), x[p.x * 64 + lane], a0);
    }
    float acc = (a0 + a1) + (a2 + a3);
    int o = row * 64 + lane;
    if (write_next) xn[o] = acc;
    out[o] += 0.25f * acc;
}

extern "C" void kernel_launch(void* const* d_in, const int* in_sizes, int n_in, void* d_out,
                              int out_size, void* d_ws, size_t ws_size, hipStream_t stream) {
    const int* rows = (const int*)d_in[0];
    const int* cols = (const int*)d_in[1];
    const float* vals = (const float*)d_in[2];
    const float* content = (const float*)d_in[3];
    const float* user_w = (const float*)d_in[4];
    const float* item_w = (const float*)d_in[5];
    const float* proj_w = (const float*)d_in[6];
    const float* proj_b = (const float*)d_in[7];

    const int E = in_sizes[0];
    const int NI = in_sizes[3] / 64;
    const int NU = in_sizes[4] / 64;
    const int N = NU + NI;
    float* out = (float*)d_out;

    char* ws = (char*)d_ws;
    size_t off = 0;
    auto alloc = [&](size_t b) {
        size_t o = off;
        off = (off + b + 255) & ~(size_t)255;
        return o;
    };
    float* xA = (float*)(ws + alloc((size_t)N * 64 * 4));
    float* xB = (float*)(ws + alloc((size_t)N * 64 * 4));
    int2* ecv = (int2*)(ws + alloc((size_t)E * 8));
    int* row_ptr = (int*)(ws + alloc((size_t)(N + 1) * 4));
    int* counts = (int*)(ws + alloc((size_t)N * 4));
    int* bsum = (int*)(ws + alloc(4096));

    // ---- CSR build ----
    hipMemsetAsync(counts, 0, (size_t)N * 4, stream);
    hist_kernel<<<4096, 256, 0, stream>>>(rows, counts, E);
    int nb = (N + 1023) / 1024;
    scan1_kernel<<<nb, 256, 0, stream>>>(counts, bsum, N);
    scan2_kernel<<<1, 1024, 0, stream>>>(bsum, nb, row_ptr, N, E);
    scan3_kernel<<<nb, 256, 0, stream>>>(counts, bsum, row_ptr, N);
    hipMemcpyAsync(counts, row_ptr, (size_t)N * 4, hipMemcpyDeviceToDevice, stream);
    scatter_kernel<<<4096, 256, 0, stream>>>(rows, cols, vals, counts, ecv, E);

    // ---- x0 + out init ----
    init_users_kernel<<<2048, 256, 0, stream>>>((const float4*)user_w, (float4*)xA,
                                                (float4*)out, NU * 16);
    init_items_kernel<<<(NI + 63) / 64, 256, 0, stream>>>(item_w, content, proj_w, proj_b, xA,
                                                          out, NI, NU);

    // ---- 3 propagation layers ----
    int nblk = (N + 3) / 4;
    spmm_kernel<<<nblk, 256, 0, stream>>>(row_ptr, ecv, xA, xB, out, N, 1);
    spmm_kernel<<<nblk, 256, 0, stream>>>(row_ptr, ecv, xB, xA, out, N, 1);
    spmm_kernel<<<nblk, 256, 0, stream>>>(row_ptr, ecv, xA, xB, out, N, 0);
}